// Round 17
// baseline (281.774 us; speedup 1.0000x reference)
//
#include <hip/hip_runtime.h>
#include <hip/hip_fp16.h>
#include <math.h>

__host__ __device__ static inline int div_up(long long a, long long b) { return (int)((a + b - 1) / b); }

#define SCH 2048              // scan chunk per block
#define PM 256                // edge chunks (one block per chunk in histA/partitionA)
#define BKN 256               // nodes per bucket (shift 8); buckets 256-aligned
#define CAP 8192              // LDS staging capacity (edges) in k_placeB
#define PROPG 2048            // persistent blocks for propagation

struct h8 { __half2 a, b, c, d; };   // 8 halfs = 16 B
struct h4 { __half2 a, b; };         // 4 halfs = 8 B

__device__ inline int nt_load1(const int* p) {
    return __builtin_nontemporal_load(p);
}
__device__ inline float4 h4tof4(h4 v) {
    float2 f0 = __half22float2(v.a), f1 = __half22float2(v.b);
    return make_float4(f0.x, f0.y, f1.x, f1.y);
}
__device__ inline h4 f4toh4(float4 v) {
    h4 o;
    o.a = __float22half2_rn(make_float2(v.x, v.y));
    o.b = __float22half2_rn(make_float2(v.z, v.w));
    return o;
}

// ---------------- CSR build (zero per-edge global atomics) ----------------

// Bucket-level LDS histogram of dst; out slice-major histA[b*PM + c].
__global__ __launch_bounds__(256) void k_histA(const int* __restrict__ dst,
                                               int* __restrict__ histA,
                                               int E, int NBK) {
    __shared__ int h[1024];               // NBK <= 1024
    const int tid = threadIdx.x, c = blockIdx.x;
    for (int i = tid; i < NBK; i += 256) h[i] = 0;
    __syncthreads();
    const int ce = (div_up(E, PM) + 3) & ~3;
    const int e0 = c * ce, e1 = min(E, e0 + ce);
    int i = e0 + tid * 4;
    for (; i + 3 < e1; i += 256 * 4) {
        int4 d = *reinterpret_cast<const int4*>(dst + i);
        atomicAdd(&h[d.x >> 8], 1);
        atomicAdd(&h[d.y >> 8], 1);
        atomicAdd(&h[d.z >> 8], 1);
        atomicAdd(&h[d.w >> 8], 1);
    }
    for (int j = i; j < e1; ++j) atomicAdd(&h[dst[j] >> 8], 1);
    __syncthreads();
    for (int b = tid; b < NBK; b += 256) histA[b * PM + c] = h[b];
}

// Scan phase 1: per-block sums of SCH-element chunks (generic length).
__global__ void k_scan_part(const int* __restrict__ a, int* __restrict__ bsum, int len) {
    __shared__ int ws[4];
    int base = blockIdx.x * SCH + threadIdx.x * 8;
    int t = 0;
#pragma unroll
    for (int j = 0; j < 8; ++j) {
        int idx = base + j;
        if (idx < len) t += a[idx];
    }
    for (int off = 32; off >= 1; off >>= 1) t += __shfl_xor(t, off);
    int lane = threadIdx.x & 63, wid = threadIdx.x >> 6;
    if (lane == 0) ws[wid] = t;
    __syncthreads();
    if (threadIdx.x == 0) bsum[blockIdx.x] = ws[0] + ws[1] + ws[2] + ws[3];
}

// Scan phase 2 (block sums, NB <= 1024) + grand total -> tot[0].
__global__ void k_scan_bsums(int* __restrict__ bsum, int* __restrict__ tot, int NB) {
    __shared__ int wsum[16];
    int tid = threadIdx.x;
    int v = (tid < NB) ? bsum[tid] : 0;
    int lane = tid & 63, wid = tid >> 6;
    int x = v;
    for (int off = 1; off < 64; off <<= 1) {
        int y = __shfl_up(x, off);
        if (lane >= off) x += y;
    }
    if (lane == 63) wsum[wid] = x;
    __syncthreads();
    if (tid < 16) {
        int s = wsum[tid];
        for (int off = 1; off < 16; off <<= 1) {
            int y = __shfl_up(s, off);
            if (tid >= off) s += y;
        }
        wsum[tid] = s;
    }
    __syncthreads();
    int woff = (wid > 0) ? wsum[wid - 1] : 0;
    int excl = woff + x - v;
    if (tid < NB) bsum[tid] = excl;
    if (tid == NB - 1) tot[0] = excl + v;
}

// Scan phase 3 (node variant): emits rp, cur, dis, inv.
__global__ void k_scan_apply(const int* __restrict__ cnt, const int* __restrict__ bsum,
                             int* __restrict__ rp, int* __restrict__ cur,
                             float* __restrict__ dis, float* __restrict__ inv, int N) {
    __shared__ int wsum[4];
    int tid = threadIdx.x;
    int base = blockIdx.x * SCH + tid * 8;
    int v[8];
    int t = 0;
#pragma unroll
    for (int j = 0; j < 8; ++j) {
        int idx = base + j;
        v[j] = (idx < N) ? cnt[idx] : 0;
        t += v[j];
    }
    int lane = tid & 63, wid = tid >> 6;
    int x = t;
    for (int off = 1; off < 64; off <<= 1) {
        int y = __shfl_up(x, off);
        if (lane >= off) x += y;
    }
    if (lane == 63) wsum[wid] = x;
    __syncthreads();
    int woff = 0;
    for (int w = 0; w < wid; ++w) woff += wsum[w];
    int run = bsum[blockIdx.x] + woff + (x - t);
#pragma unroll
    for (int j = 0; j < 8; ++j) {
        int idx = base + j;
        if (idx < N) {
            rp[idx] = run;
            cur[idx] = run;
            float dg = (float)v[j] + 1.0f;
            dis[idx] = rsqrtf(dg);
            inv[idx] = sqrtf(dg);
        }
        run += v[j];
    }
}

// Scan phase 3 (plain, in-place): a <- exclusive_scan(a).
__global__ void k_scan_apply_plain(int* __restrict__ a, const int* __restrict__ bsum,
                                   int len) {
    __shared__ int wsum[4];
    int tid = threadIdx.x;
    int base = blockIdx.x * SCH + tid * 8;
    int v[8];
    int t = 0;
#pragma unroll
    for (int j = 0; j < 8; ++j) {
        int idx = base + j;
        v[j] = (idx < len) ? a[idx] : 0;
        t += v[j];
    }
    int lane = tid & 63, wid = tid >> 6;
    int x = t;
    for (int off = 1; off < 64; off <<= 1) {
        int y = __shfl_up(x, off);
        if (lane >= off) x += y;
    }
    if (lane == 63) wsum[wid] = x;
    __syncthreads();
    int woff = 0;
    for (int w = 0; w < wid; ++w) woff += wsum[w];
    int run = bsum[blockIdx.x] + woff + (x - t);
#pragma unroll
    for (int j = 0; j < 8; ++j) {
        int idx = base + j;
        if (idx < len) a[idx] = run;
        run += v[j];
    }
}

// Partition edges into per-(bucket,chunk) regions via LDS cursors, packed
// uint32 = (src << 8) | (dst & 255). Valid: N < 2^24, buckets 256-aligned.
__global__ __launch_bounds__(256) void k_partitionA(
        const int* __restrict__ src, const int* __restrict__ dst,
        const int* __restrict__ pbase, unsigned* __restrict__ pairs, int E, int NBK) {
    __shared__ int curb[1024];
    const int tid = threadIdx.x, c = blockIdx.x;
    for (int b = tid; b < NBK; b += 256) curb[b] = pbase[b * PM + c];
    __syncthreads();
    const int ce = (div_up(E, PM) + 3) & ~3;
    const int e0 = c * ce, e1 = min(E, e0 + ce);
    int i = e0 + tid * 4;
    for (; i + 3 < e1; i += 256 * 4) {
        int4 d4 = *reinterpret_cast<const int4*>(dst + i);
        int4 s4 = *reinterpret_cast<const int4*>(src + i);
        int p0 = atomicAdd(&curb[d4.x >> 8], 1); pairs[p0] = ((unsigned)s4.x << 8) | (d4.x & 255);
        int p1 = atomicAdd(&curb[d4.y >> 8], 1); pairs[p1] = ((unsigned)s4.y << 8) | (d4.y & 255);
        int p2 = atomicAdd(&curb[d4.z >> 8], 1); pairs[p2] = ((unsigned)s4.z << 8) | (d4.z & 255);
        int p3 = atomicAdd(&curb[d4.w >> 8], 1); pairs[p3] = ((unsigned)s4.w << 8) | (d4.w & 255);
    }
    for (int j = i; j < e1; ++j) {
        int d = dst[j];
        int p = atomicAdd(&curb[d >> 8], 1);
        pairs[p] = ((unsigned)src[j] << 8) | (d & 255);
    }
}

// Per-node degree counts from the bucketed pairs: LDS counters, dense write.
__global__ __launch_bounds__(256) void k_cntB(
        const unsigned* __restrict__ pairs, const int* __restrict__ pbase,
        int* __restrict__ cnt, int E, int N, int NBK) {
    __shared__ int c256[BKN];
    const int b = blockIdx.x;
    const int tid = threadIdx.x;
    c256[tid] = 0;
    __syncthreads();
    const int base = pbase[b * PM];
    const int end = (b + 1 < NBK) ? pbase[(b + 1) * PM] : E;
    for (int i = base + tid; i < end; i += 256)
        atomicAdd(&c256[pairs[i] & 255], 1);
    __syncthreads();
    int n = b * BKN + tid;
    if (n < N) cnt[n] = c256[tid];
}

// Final place: one block per bucket; LDS counting-sort -> coalesced csrc write.
__global__ __launch_bounds__(256) void k_placeB(
        const unsigned* __restrict__ pairs, const int* __restrict__ rp,
        int* __restrict__ cur, int* __restrict__ csrc, int N) {
    __shared__ int curl[BKN];
    __shared__ int stage[CAP];
    const int b = blockIdx.x;
    const int n0 = b * BKN;
    const int n1 = min(N, n0 + BKN);
    const int base = rp[n0], end = rp[n1];
    const int cntb = end - base;
    const int tid = threadIdx.x;
    if (cntb <= CAP) {
        if (n0 + tid < n1) curl[tid] = rp[n0 + tid] - base;
        __syncthreads();
        for (int i = base + tid; i < end; i += 256) {
            unsigned pr = pairs[i];
            int p = atomicAdd(&curl[pr & 255], 1);
            stage[p] = (int)(pr >> 8);
        }
        __syncthreads();
        for (int i = tid; i < cntb; i += 256) csrc[base + i] = stage[i];
    } else {
        for (int i = base + tid; i < end; i += 256) {
            unsigned pr = pairs[i];
            int d = n0 + (int)(pr & 255);
            csrc[atomicAdd(&cur[d], 1)] = (int)(pr >> 8);
        }
    }
}

// ---------------- propagation (scaled form: buffers hold h' = dis*h) ----------------
// h_out'[n] = dis[n]^2 * ( h'[n] + sum_{s in N(n)} h'[s] )  -- no per-edge weights.

__device__ inline void add_h8(float* acc, const h8& v) {
    float2 f0 = __half22float2(v.a), f1 = __half22float2(v.b);
    float2 f2 = __half22float2(v.c), f3 = __half22float2(v.d);
    acc[0] += f0.x; acc[1] += f0.y;
    acc[2] += f1.x; acc[3] += f1.y;
    acc[4] += f2.x; acc[5] += f2.y;
    acc[6] += f3.x; acc[7] += f3.y;
}

template<int F>  // F in halfs per row; TPE = F/8
__global__ __launch_bounds__(256) void k_prop_h(
        const int* __restrict__ rp, const int* __restrict__ csrc,
        const float* __restrict__ dis,
        const __half* __restrict__ hin, __half* __restrict__ hout, int N) {
    constexpr int TPE = F / 8;
    const long long total = (long long)N * TPE;
    const long long stride = (long long)gridDim.x * 256;
    for (long long t = (long long)blockIdx.x * 256 + threadIdx.x; t < total; t += stride) {
        int n = (int)(t / TPE);
        int l = (int)(t % TPE);
        float acc[8];
        {
            h8 v = *reinterpret_cast<const h8*>(hin + (size_t)n * F + 8 * l);
#pragma unroll
            for (int j = 0; j < 8; ++j) acc[j] = 0.f;
            add_h8(acc, v);
        }
        int e = rp[n], end = rp[n + 1];
        for (; e + 7 < end; e += 8) {
            int s[8];
            h8 v[8];
#pragma unroll
            for (int j = 0; j < 8; ++j) s[j] = nt_load1(csrc + e + j);
#pragma unroll
            for (int j = 0; j < 8; ++j)
                v[j] = *reinterpret_cast<const h8*>(hin + (size_t)s[j] * F + 8 * l);
#pragma unroll
            for (int j = 0; j < 8; ++j) add_h8(acc, v[j]);
        }
        for (; e < end; ++e) {
            int s = nt_load1(csrc + e);
            h8 v = *reinterpret_cast<const h8*>(hin + (size_t)s * F + 8 * l);
            add_h8(acc, v);
        }
        float dn = dis[n];
        float d2 = dn * dn;
        h8 o;
        o.a = __float22half2_rn(make_float2(acc[0] * d2, acc[1] * d2));
        o.b = __float22half2_rn(make_float2(acc[2] * d2, acc[3] * d2));
        o.c = __float22half2_rn(make_float2(acc[4] * d2, acc[5] * d2));
        o.d = __float22half2_rn(make_float2(acc[6] * d2, acc[7] * d2));
        *reinterpret_cast<h8*>(hout + (size_t)n * F + 8 * l) = o;
    }
}

// ---------------- dense layers (register-tiled) ----------------

#define FMA4(a, s, v) { (a).x += (s) * (v).x; (a).y += (s) * (v).y; \
                        (a).z += (s) * (v).z; (a).w += (s) * (v).w; }

// Y'[n,h] = dis[n] * (X[n,:128] @ W[:,h]), fp16 out. fp16 LDS staging (35KB)
// -> 4 blocks/CU (was 67KB fp32 -> 2 blocks/CU, 16% occupancy).
__global__ __launch_bounds__(256) void k_gemm1(const float* __restrict__ X,
                                               const float* __restrict__ W,
                                               const float* __restrict__ dis,
                                               __half* __restrict__ Y, int N) {
    __shared__ __half sx[64][132];
    __shared__ __half sw[128][72];
    const int tid = threadIdx.x;
    const int n0 = blockIdx.x * 64;
    const bool full = (n0 + 64 <= N);
#pragma unroll
    for (int j = 0; j < 8; ++j) {
        int idx = (tid + j * 256) * 4;
        int k = idx >> 6, h = idx & 63;
        float4 v = *reinterpret_cast<const float4*>(W + idx);
        *reinterpret_cast<h4*>(&sw[k][h]) = f4toh4(v);
    }
#pragma unroll
    for (int j = 0; j < 8; ++j) {
        int idx = (tid + j * 256) * 4;
        int n = idx >> 7, k = idx & 127;
        float4 v = make_float4(0.f, 0.f, 0.f, 0.f);
        if (full || n0 + n < N)
            v = *reinterpret_cast<const float4*>(X + (size_t)(n0 + n) * 128 + k);
        *reinterpret_cast<h4*>(&sx[n][k]) = f4toh4(v);
    }
    __syncthreads();
    const int lane = tid & 63, wid = tid >> 6;
    const int h0 = (lane & 15) * 4;
    const int nb = wid * 16 + (lane >> 4) * 4;
    float4 a0 = {0,0,0,0}, a1 = {0,0,0,0}, a2 = {0,0,0,0}, a3 = {0,0,0,0};
#pragma unroll 4
    for (int k0 = 0; k0 < 128; k0 += 4) {
        float4 x0 = h4tof4(*reinterpret_cast<h4*>(&sx[nb + 0][k0]));
        float4 x1 = h4tof4(*reinterpret_cast<h4*>(&sx[nb + 1][k0]));
        float4 x2 = h4tof4(*reinterpret_cast<h4*>(&sx[nb + 2][k0]));
        float4 x3 = h4tof4(*reinterpret_cast<h4*>(&sx[nb + 3][k0]));
        float4 w0 = h4tof4(*reinterpret_cast<h4*>(&sw[k0 + 0][h0]));
        float4 w1 = h4tof4(*reinterpret_cast<h4*>(&sw[k0 + 1][h0]));
        float4 w2 = h4tof4(*reinterpret_cast<h4*>(&sw[k0 + 2][h0]));
        float4 w3 = h4tof4(*reinterpret_cast<h4*>(&sw[k0 + 3][h0]));
        FMA4(a0, x0.x, w0); FMA4(a0, x0.y, w1); FMA4(a0, x0.z, w2); FMA4(a0, x0.w, w3);
        FMA4(a1, x1.x, w0); FMA4(a1, x1.y, w1); FMA4(a1, x1.z, w2); FMA4(a1, x1.w, w3);
        FMA4(a2, x2.x, w0); FMA4(a2, x2.y, w1); FMA4(a2, x2.z, w2); FMA4(a2, x2.w, w3);
        FMA4(a3, x3.x, w0); FMA4(a3, x3.y, w1); FMA4(a3, x3.z, w2); FMA4(a3, x3.w, w3);
    }
    int n = n0 + nb;
#pragma unroll
    for (int r = 0; r < 4; ++r) {
        float4 a = (r == 0) ? a0 : (r == 1) ? a1 : (r == 2) ? a2 : a3;
        if (n + r < N) {
            float sc = dis[n + r];
            h4 o;
            o.a = __float22half2_rn(make_float2(a.x * sc, a.y * sc));
            o.b = __float22half2_rn(make_float2(a.z * sc, a.w * sc));
            *reinterpret_cast<h4*>(Y + (size_t)(n + r) * 64 + h0) = o;
        }
    }
}

// T'[n,c] = dis[n] * ( relu(inv[n]*H'[n,:64]+b1) @ W2[:,c] ); scaled fp16 in/out.
__global__ __launch_bounds__(256) void k_gemm2(const __half* __restrict__ H,
                                               const float* __restrict__ b1,
                                               const float* __restrict__ W2,
                                               const float* __restrict__ dis,
                                               const float* __restrict__ inv,
                                               __half* __restrict__ T, int N) {
    __shared__ float sh[64][68];
    __shared__ float sw[64][68];
    const int tid = threadIdx.x;
    const int n0 = blockIdx.x * 64;
    const bool full = (n0 + 64 <= N);
#pragma unroll
    for (int j = 0; j < 4; ++j) {
        int idx = (tid + j * 256) * 4;
        int k = idx >> 6, h = idx & 63;
        float4 v = make_float4(0.f, 0.f, 0.f, 0.f);
        if (h < 40) v = *reinterpret_cast<const float4*>(W2 + k * 40 + h);
        *reinterpret_cast<float4*>(&sw[k][h]) = v;
    }
#pragma unroll
    for (int j = 0; j < 2; ++j) {
        int idx = (tid + j * 256) * 8;
        int n = idx >> 6, k = idx & 63;
        float v[8];
        if (full || n0 + n < N) {
            float iv = inv[n0 + n];
            h8 hv = *reinterpret_cast<const h8*>(H + (size_t)(n0 + n) * 64 + k);
            float2 f0 = __half22float2(hv.a), f1 = __half22float2(hv.b);
            float2 f2 = __half22float2(hv.c), f3 = __half22float2(hv.d);
            v[0] = f0.x; v[1] = f0.y; v[2] = f1.x; v[3] = f1.y;
            v[4] = f2.x; v[5] = f2.y; v[6] = f3.x; v[7] = f3.y;
#pragma unroll
            for (int q = 0; q < 8; ++q) v[q] = fmaxf(v[q] * iv + b1[k + q], 0.f);
        } else {
#pragma unroll
            for (int q = 0; q < 8; ++q) v[q] = 0.f;
        }
#pragma unroll
        for (int q = 0; q < 8; ++q) sh[n][k + q] = v[q];
    }
    __syncthreads();
    const int lane = tid & 63, wid = tid >> 6;
    const int h0 = (lane & 15) * 4;
    const int nb = wid * 16 + (lane >> 4) * 4;
    float4 a0 = {0,0,0,0}, a1 = {0,0,0,0}, a2 = {0,0,0,0}, a3 = {0,0,0,0};
#pragma unroll 4
    for (int k0 = 0; k0 < 64; k0 += 4) {
        float4 x0 = *reinterpret_cast<float4*>(&sh[nb + 0][k0]);
        float4 x1 = *reinterpret_cast<float4*>(&sh[nb + 1][k0]);
        float4 x2 = *reinterpret_cast<float4*>(&sh[nb + 2][k0]);
        float4 x3 = *reinterpret_cast<float4*>(&sh[nb + 3][k0]);
        float4 w0 = *reinterpret_cast<float4*>(&sw[k0 + 0][h0]);
        float4 w1 = *reinterpret_cast<float4*>(&sw[k0 + 1][h0]);
        float4 w2 = *reinterpret_cast<float4*>(&sw[k0 + 2][h0]);
        float4 w3 = *reinterpret_cast<float4*>(&sw[k0 + 3][h0]);
        FMA4(a0, x0.x, w0); FMA4(a0, x0.y, w1); FMA4(a0, x0.z, w2); FMA4(a0, x0.w, w3);
        FMA4(a1, x1.x, w0); FMA4(a1, x1.y, w1); FMA4(a1, x1.z, w2); FMA4(a1, x1.w, w3);
        FMA4(a2, x2.x, w0); FMA4(a2, x2.y, w1); FMA4(a2, x2.z, w2); FMA4(a2, x2.w, w3);
        FMA4(a3, x3.x, w0); FMA4(a3, x3.y, w1); FMA4(a3, x3.z, w2); FMA4(a3, x3.w, w3);
    }
    if (h0 < 40) {
        int n = n0 + nb;
#pragma unroll
        for (int r = 0; r < 4; ++r) {
            float4 a = (r == 0) ? a0 : (r == 1) ? a1 : (r == 2) ? a2 : a3;
            if (n + r < N) {
                float sc = dis[n + r];
                h4 o;
                o.a = __float22half2_rn(make_float2(a.x * sc, a.y * sc));
                o.b = __float22half2_rn(make_float2(a.z * sc, a.w * sc));
                *reinterpret_cast<h4*>(T + (size_t)(n + r) * 40 + h0) = o;
            }
        }
    }
}

// out[n,c] = log_softmax(inv[n]*T'[n,:40] + b2), T' scaled fp16. One wave/node.
__global__ void k_bias_lsm(const __half* __restrict__ T, const float* __restrict__ b2,
                           const float* __restrict__ inv, float* __restrict__ Y, int N) {
    int gid = blockIdx.x * blockDim.x + threadIdx.x;
    int node = gid >> 6;
    int lane = threadIdx.x & 63;
    if (node >= N) return;
    float iv = inv[node];
    float v = (lane < 40) ? __half2float(T[(size_t)node * 40 + lane]) * iv + b2[lane]
                          : -INFINITY;
    float m = v;
    for (int off = 32; off >= 1; off >>= 1) m = fmaxf(m, __shfl_xor(m, off));
    float ev = (lane < 40) ? expf(v - m) : 0.0f;
    float s = ev;
    for (int off = 32; off >= 1; off >>= 1) s += __shfl_xor(s, off);
    if (lane < 40) Y[(size_t)node * 40 + lane] = v - m - logf(s);
}

// ---------------- launch ----------------

extern "C" void kernel_launch(void* const* d_in, const int* in_sizes, int n_in,
                              void* d_out, int out_size, void* d_ws, size_t ws_size,
                              hipStream_t stream) {
    const float* x  = (const float*)d_in[0];
    const int*   ei = (const int*)d_in[1];
    const float* W1 = (const float*)d_in[2];
    const float* b1 = (const float*)d_in[3];
    const float* W2 = (const float*)d_in[4];
    const float* b2 = (const float*)d_in[5];
    float* out = (float*)d_out;

    const int H = in_sizes[3];            // 64
    const int F = in_sizes[2] / H;        // 128
    const int N = in_sizes[0] / F;        // 100000
    const int E = in_sizes[1] / 2;        // 1600000
    (void)ws_size; (void)n_in; (void)out_size;

    const int* src = ei;
    const int* dst = ei + E;
    const int NSB = div_up(N, SCH);               // node-scan blocks (49)
    const int NBK = div_up(N, BKN);               // node buckets (391)
    const int lenA = NBK * PM;                    // histA length (100096)
    const int NSA = div_up(lenA, SCH);            // histA-scan blocks (49)

    // workspace layout
    const int Npad = (N + 256) & ~255;            // covers N+1
    float* dis   = (float*)d_ws;                  // N
    float* inv   = dis + Npad;                    // N
    int*   cnt   = (int*)(inv + Npad);            // N
    int*   rp    = cnt + Npad;                    // N+1
    int*   cur   = rp + Npad;                     // N
    int*   bsum  = cur + Npad;                    // 256 pad
    int*   bsumA = bsum + 256;                    // 256 pad (tot at +128)
    int*   histA = bsumA + 256;                   // lenA
    int*   csrc  = histA + ((lenA + 255) & ~255); // E
    __half* bufA = (__half*)(csrc + ((E + 255) & ~255));   // N*64 halfs
    __half* bufB = bufA + (size_t)N * 64;                  // N*64 halfs
    unsigned* pairs = (unsigned*)bufB;            // E u32, dead until prop1

    const int B = 256;

    // ---- CSR build (no per-edge global atomics anywhere) ----
    k_histA<<<PM, 256, 0, stream>>>(dst, histA, E, NBK);
    k_scan_part<<<NSA, 256, 0, stream>>>(histA, bsumA, lenA);
    k_scan_bsums<<<1, 1024, 0, stream>>>(bsumA, bsumA + 128, NSA);
    k_scan_apply_plain<<<NSA, 256, 0, stream>>>(histA, bsumA, lenA);
    k_partitionA<<<PM, 256, 0, stream>>>(src, dst, histA, pairs, E, NBK);
    k_cntB<<<NBK, 256, 0, stream>>>(pairs, histA, cnt, E, N, NBK);
    k_scan_part<<<NSB, 256, 0, stream>>>(cnt, bsum, N);
    k_scan_bsums<<<1, 1024, 0, stream>>>(bsum, rp + N, NSB);
    k_scan_apply<<<NSB, 256, 0, stream>>>(cnt, bsum, rp, cur, dis, inv, N);
    k_placeB<<<NBK, 256, 0, stream>>>(pairs, rp, cur, csrc, N);

    // ---- layer 1 (commuted, scaled form): Y' = dis*(X@W1), 2 props at F=64 ----
    k_gemm1<<<div_up(N, 64), 256, 0, stream>>>(x, W1, dis, bufA, N);
    k_prop_h<64><<<PROPG, B, 0, stream>>>(rp, csrc, dis, bufA, bufB, N);
    k_prop_h<64><<<PROPG, B, 0, stream>>>(rp, csrc, dis, bufB, bufA, N);

    // ---- layer 2 (commuted, scaled form): T' = dis*(relu(inv*h'+b1)@W2), 2 props F=40 ----
    k_gemm2<<<div_up(N, 64), 256, 0, stream>>>(bufA, b1, W2, dis, inv, bufB, N);
    k_prop_h<40><<<PROPG, B, 0, stream>>>(rp, csrc, dis, bufB, bufA, N);
    k_prop_h<40><<<PROPG, B, 0, stream>>>(rp, csrc, dis, bufA, bufB, N);

    // ---- epilogue: out = log_softmax(inv*T' + b2) ----
    k_bias_lsm<<<div_up((long long)N * 64, 256), 256, 0, stream>>>(bufB, b2, inv, out, N);
}

// Round 18
// 271.104 us; speedup vs baseline: 1.0394x; 1.0394x over previous
//
#include <hip/hip_runtime.h>
#include <hip/hip_fp16.h>
#include <math.h>

__host__ __device__ static inline int div_up(long long a, long long b) { return (int)((a + b - 1) / b); }

#define SCH 2048              // scan chunk per block
#define PM 256                // edge chunks (one block per chunk in histA/partitionA)
#define BKN 256               // nodes per bucket (shift 8); buckets 256-aligned
#define CAP 8192              // LDS staging capacity (edges) in k_placeB
#define PROPG 2048            // persistent blocks for propagation

struct h8 { __half2 a, b, c, d; };   // 8 halfs = 16 B
struct h4 { __half2 a, b; };         // 4 halfs = 8 B

typedef _Float16 half8v __attribute__((ext_vector_type(8)));
typedef float f32x4v __attribute__((ext_vector_type(4)));

__device__ inline int nt_load1(const int* p) {
    return __builtin_nontemporal_load(p);
}
__device__ inline h4 f4toh4(float4 v) {
    h4 o;
    o.a = __float22half2_rn(make_float2(v.x, v.y));
    o.b = __float22half2_rn(make_float2(v.z, v.w));
    return o;
}

// ---------------- CSR build (zero per-edge global atomics) ----------------

// Bucket-level LDS histogram of dst; out slice-major histA[b*PM + c].
__global__ __launch_bounds__(256) void k_histA(const int* __restrict__ dst,
                                               int* __restrict__ histA,
                                               int E, int NBK) {
    __shared__ int h[1024];               // NBK <= 1024
    const int tid = threadIdx.x, c = blockIdx.x;
    for (int i = tid; i < NBK; i += 256) h[i] = 0;
    __syncthreads();
    const int ce = (div_up(E, PM) + 3) & ~3;
    const int e0 = c * ce, e1 = min(E, e0 + ce);
    int i = e0 + tid * 4;
    for (; i + 3 < e1; i += 256 * 4) {
        int4 d = *reinterpret_cast<const int4*>(dst + i);
        atomicAdd(&h[d.x >> 8], 1);
        atomicAdd(&h[d.y >> 8], 1);
        atomicAdd(&h[d.z >> 8], 1);
        atomicAdd(&h[d.w >> 8], 1);
    }
    for (int j = i; j < e1; ++j) atomicAdd(&h[dst[j] >> 8], 1);
    __syncthreads();
    for (int b = tid; b < NBK; b += 256) histA[b * PM + c] = h[b];
}

// Scan phase 1: per-block sums of SCH-element chunks (generic length).
__global__ void k_scan_part(const int* __restrict__ a, int* __restrict__ bsum, int len) {
    __shared__ int ws[4];
    int base = blockIdx.x * SCH + threadIdx.x * 8;
    int t = 0;
#pragma unroll
    for (int j = 0; j < 8; ++j) {
        int idx = base + j;
        if (idx < len) t += a[idx];
    }
    for (int off = 32; off >= 1; off >>= 1) t += __shfl_xor(t, off);
    int lane = threadIdx.x & 63, wid = threadIdx.x >> 6;
    if (lane == 0) ws[wid] = t;
    __syncthreads();
    if (threadIdx.x == 0) bsum[blockIdx.x] = ws[0] + ws[1] + ws[2] + ws[3];
}

// Scan phase 2 (block sums, NB <= 1024) + grand total -> tot[0].
__global__ void k_scan_bsums(int* __restrict__ bsum, int* __restrict__ tot, int NB) {
    __shared__ int wsum[16];
    int tid = threadIdx.x;
    int v = (tid < NB) ? bsum[tid] : 0;
    int lane = tid & 63, wid = tid >> 6;
    int x = v;
    for (int off = 1; off < 64; off <<= 1) {
        int y = __shfl_up(x, off);
        if (lane >= off) x += y;
    }
    if (lane == 63) wsum[wid] = x;
    __syncthreads();
    if (tid < 16) {
        int s = wsum[tid];
        for (int off = 1; off < 16; off <<= 1) {
            int y = __shfl_up(s, off);
            if (tid >= off) s += y;
        }
        wsum[tid] = s;
    }
    __syncthreads();
    int woff = (wid > 0) ? wsum[wid - 1] : 0;
    int excl = woff + x - v;
    if (tid < NB) bsum[tid] = excl;
    if (tid == NB - 1) tot[0] = excl + v;
}

// Scan phase 3 (node variant): emits rp, cur, dis, inv.
__global__ void k_scan_apply(const int* __restrict__ cnt, const int* __restrict__ bsum,
                             int* __restrict__ rp, int* __restrict__ cur,
                             float* __restrict__ dis, float* __restrict__ inv, int N) {
    __shared__ int wsum[4];
    int tid = threadIdx.x;
    int base = blockIdx.x * SCH + tid * 8;
    int v[8];
    int t = 0;
#pragma unroll
    for (int j = 0; j < 8; ++j) {
        int idx = base + j;
        v[j] = (idx < N) ? cnt[idx] : 0;
        t += v[j];
    }
    int lane = tid & 63, wid = tid >> 6;
    int x = t;
    for (int off = 1; off < 64; off <<= 1) {
        int y = __shfl_up(x, off);
        if (lane >= off) x += y;
    }
    if (lane == 63) wsum[wid] = x;
    __syncthreads();
    int woff = 0;
    for (int w = 0; w < wid; ++w) woff += wsum[w];
    int run = bsum[blockIdx.x] + woff + (x - t);
#pragma unroll
    for (int j = 0; j < 8; ++j) {
        int idx = base + j;
        if (idx < N) {
            rp[idx] = run;
            cur[idx] = run;
            float dg = (float)v[j] + 1.0f;
            dis[idx] = rsqrtf(dg);
            inv[idx] = sqrtf(dg);
        }
        run += v[j];
    }
}

// Scan phase 3 (plain, in-place): a <- exclusive_scan(a).
__global__ void k_scan_apply_plain(int* __restrict__ a, const int* __restrict__ bsum,
                                   int len) {
    __shared__ int wsum[4];
    int tid = threadIdx.x;
    int base = blockIdx.x * SCH + tid * 8;
    int v[8];
    int t = 0;
#pragma unroll
    for (int j = 0; j < 8; ++j) {
        int idx = base + j;
        v[j] = (idx < len) ? a[idx] : 0;
        t += v[j];
    }
    int lane = tid & 63, wid = tid >> 6;
    int x = t;
    for (int off = 1; off < 64; off <<= 1) {
        int y = __shfl_up(x, off);
        if (lane >= off) x += y;
    }
    if (lane == 63) wsum[wid] = x;
    __syncthreads();
    int woff = 0;
    for (int w = 0; w < wid; ++w) woff += wsum[w];
    int run = bsum[blockIdx.x] + woff + (x - t);
#pragma unroll
    for (int j = 0; j < 8; ++j) {
        int idx = base + j;
        if (idx < len) a[idx] = run;
        run += v[j];
    }
}

// Partition edges into per-(bucket,chunk) regions via LDS cursors, packed
// uint32 = (src << 8) | (dst & 255). Valid: N < 2^24, buckets 256-aligned.
__global__ __launch_bounds__(256) void k_partitionA(
        const int* __restrict__ src, const int* __restrict__ dst,
        const int* __restrict__ pbase, unsigned* __restrict__ pairs, int E, int NBK) {
    __shared__ int curb[1024];
    const int tid = threadIdx.x, c = blockIdx.x;
    for (int b = tid; b < NBK; b += 256) curb[b] = pbase[b * PM + c];
    __syncthreads();
    const int ce = (div_up(E, PM) + 3) & ~3;
    const int e0 = c * ce, e1 = min(E, e0 + ce);
    int i = e0 + tid * 4;
    for (; i + 3 < e1; i += 256 * 4) {
        int4 d4 = *reinterpret_cast<const int4*>(dst + i);
        int4 s4 = *reinterpret_cast<const int4*>(src + i);
        int p0 = atomicAdd(&curb[d4.x >> 8], 1); pairs[p0] = ((unsigned)s4.x << 8) | (d4.x & 255);
        int p1 = atomicAdd(&curb[d4.y >> 8], 1); pairs[p1] = ((unsigned)s4.y << 8) | (d4.y & 255);
        int p2 = atomicAdd(&curb[d4.z >> 8], 1); pairs[p2] = ((unsigned)s4.z << 8) | (d4.z & 255);
        int p3 = atomicAdd(&curb[d4.w >> 8], 1); pairs[p3] = ((unsigned)s4.w << 8) | (d4.w & 255);
    }
    for (int j = i; j < e1; ++j) {
        int d = dst[j];
        int p = atomicAdd(&curb[d >> 8], 1);
        pairs[p] = ((unsigned)src[j] << 8) | (d & 255);
    }
}

// Per-node degree counts from the bucketed pairs: LDS counters, dense write.
__global__ __launch_bounds__(256) void k_cntB(
        const unsigned* __restrict__ pairs, const int* __restrict__ pbase,
        int* __restrict__ cnt, int E, int N, int NBK) {
    __shared__ int c256[BKN];
    const int b = blockIdx.x;
    const int tid = threadIdx.x;
    c256[tid] = 0;
    __syncthreads();
    const int base = pbase[b * PM];
    const int end = (b + 1 < NBK) ? pbase[(b + 1) * PM] : E;
    for (int i = base + tid; i < end; i += 256)
        atomicAdd(&c256[pairs[i] & 255], 1);
    __syncthreads();
    int n = b * BKN + tid;
    if (n < N) cnt[n] = c256[tid];
}

// Final place: one block per bucket; LDS counting-sort -> coalesced csrc write.
__global__ __launch_bounds__(256) void k_placeB(
        const unsigned* __restrict__ pairs, const int* __restrict__ rp,
        int* __restrict__ cur, int* __restrict__ csrc, int N) {
    __shared__ int curl[BKN];
    __shared__ int stage[CAP];
    const int b = blockIdx.x;
    const int n0 = b * BKN;
    const int n1 = min(N, n0 + BKN);
    const int base = rp[n0], end = rp[n1];
    const int cntb = end - base;
    const int tid = threadIdx.x;
    if (cntb <= CAP) {
        if (n0 + tid < n1) curl[tid] = rp[n0 + tid] - base;
        __syncthreads();
        for (int i = base + tid; i < end; i += 256) {
            unsigned pr = pairs[i];
            int p = atomicAdd(&curl[pr & 255], 1);
            stage[p] = (int)(pr >> 8);
        }
        __syncthreads();
        for (int i = tid; i < cntb; i += 256) csrc[base + i] = stage[i];
    } else {
        for (int i = base + tid; i < end; i += 256) {
            unsigned pr = pairs[i];
            int d = n0 + (int)(pr & 255);
            csrc[atomicAdd(&cur[d], 1)] = (int)(pr >> 8);
        }
    }
}

// ---------------- propagation (scaled form: buffers hold h' = dis*h) ----------------
// h_out'[n] = dis[n]^2 * ( h'[n] + sum_{s in N(n)} h'[s] )  -- no per-edge weights.

__device__ inline void add_h8(float* acc, const h8& v) {
    float2 f0 = __half22float2(v.a), f1 = __half22float2(v.b);
    float2 f2 = __half22float2(v.c), f3 = __half22float2(v.d);
    acc[0] += f0.x; acc[1] += f0.y;
    acc[2] += f1.x; acc[3] += f1.y;
    acc[4] += f2.x; acc[5] += f2.y;
    acc[6] += f3.x; acc[7] += f3.y;
}

template<int F>  // F in halfs per row; TPE = F/8
__global__ __launch_bounds__(256) void k_prop_h(
        const int* __restrict__ rp, const int* __restrict__ csrc,
        const float* __restrict__ dis,
        const __half* __restrict__ hin, __half* __restrict__ hout, int N) {
    constexpr int TPE = F / 8;
    const long long total = (long long)N * TPE;
    const long long stride = (long long)gridDim.x * 256;
    for (long long t = (long long)blockIdx.x * 256 + threadIdx.x; t < total; t += stride) {
        int n = (int)(t / TPE);
        int l = (int)(t % TPE);
        float acc[8];
        {
            h8 v = *reinterpret_cast<const h8*>(hin + (size_t)n * F + 8 * l);
#pragma unroll
            for (int j = 0; j < 8; ++j) acc[j] = 0.f;
            add_h8(acc, v);
        }
        int e = rp[n], end = rp[n + 1];
        for (; e + 7 < end; e += 8) {
            int s[8];
            h8 v[8];
#pragma unroll
            for (int j = 0; j < 8; ++j) s[j] = nt_load1(csrc + e + j);
#pragma unroll
            for (int j = 0; j < 8; ++j)
                v[j] = *reinterpret_cast<const h8*>(hin + (size_t)s[j] * F + 8 * l);
#pragma unroll
            for (int j = 0; j < 8; ++j) add_h8(acc, v[j]);
        }
        for (; e < end; ++e) {
            int s = nt_load1(csrc + e);
            h8 v = *reinterpret_cast<const h8*>(hin + (size_t)s * F + 8 * l);
            add_h8(acc, v);
        }
        float dn = dis[n];
        float d2 = dn * dn;
        h8 o;
        o.a = __float22half2_rn(make_float2(acc[0] * d2, acc[1] * d2));
        o.b = __float22half2_rn(make_float2(acc[2] * d2, acc[3] * d2));
        o.c = __float22half2_rn(make_float2(acc[4] * d2, acc[5] * d2));
        o.d = __float22half2_rn(make_float2(acc[6] * d2, acc[7] * d2));
        *reinterpret_cast<h8*>(hout + (size_t)n * F + 8 * l) = o;
    }
}

// ---------------- dense layers ----------------

// GEMM1 via MFMA: Y'[n,h] = dis[n] * (X[n,:128] @ W1[:,h]), fp16 out.
// One block per 64-node tile; 4 waves, each owns a 16-row slice.
// B-frags (W) loaded straight from global into VGPRs (L1/L2-hot, no LDS);
// X staged fp16 in LDS (17KB), A-frag reads 16B-aligned, 2-way banks (free).
// Frag layout (m89-verified family): A: row=lane&15, k=(lane>>4)*8+j;
// B: k=(lane>>4)*8+j, col=lane&15; C/D: col=lane&15, row=(lane>>4)*4+r.
__global__ __launch_bounds__(256) void k_gemm1(const float* __restrict__ X,
                                               const float* __restrict__ W,
                                               const float* __restrict__ dis,
                                               __half* __restrict__ Y, int N) {
    __shared__ __half sx[64][136];      // row stride 272B: 16B-aligned, 2-way banks
    const int tid = threadIdx.x;
    const int lane = tid & 63, wv = tid >> 6;
    const int n0 = blockIdx.x * 64;
    const bool full = (n0 + 64 <= N);
    const int krow = (lane >> 4) * 8;
    const int col = lane & 15;

    // B-frags: whole W (128x64) as 4 col-tiles x 4 k-steps, f32 -> f16 in regs.
    half8v bfrag[4][4];
#pragma unroll
    for (int ct = 0; ct < 4; ++ct)
#pragma unroll
        for (int ks = 0; ks < 4; ++ks)
#pragma unroll
            for (int j = 0; j < 8; ++j)
                bfrag[ct][ks][j] = (_Float16)W[(ks * 32 + krow + j) * 64 + ct * 16 + col];

    // stage X tile (reg-staged loads for MLP, then convert+write)
    float4 xr[8];
#pragma unroll
    for (int j = 0; j < 8; ++j) {
        int idx = (tid + j * 256) * 4;
        int n = idx >> 7, k = idx & 127;
        float4 v = make_float4(0.f, 0.f, 0.f, 0.f);
        if (full || n0 + n < N)
            v = *reinterpret_cast<const float4*>(X + (size_t)(n0 + n) * 128 + k);
        xr[j] = v;
    }
#pragma unroll
    for (int j = 0; j < 8; ++j) {
        int idx = (tid + j * 256) * 4;
        int n = idx >> 7, k = idx & 127;
        *reinterpret_cast<h4*>(&sx[n][k]) = f4toh4(xr[j]);
    }
    __syncthreads();

    // compute: wave wv covers rows m0..m0+15; 4 k-steps x 4 col-tiles MFMA
    const int m0 = wv * 16;
    f32x4v acc[4] = {{0,0,0,0},{0,0,0,0},{0,0,0,0},{0,0,0,0}};
#pragma unroll
    for (int ks = 0; ks < 4; ++ks) {
        half8v a = *reinterpret_cast<const half8v*>(&sx[m0 + (lane & 15)][ks * 32 + krow]);
#pragma unroll
        for (int ct = 0; ct < 4; ++ct)
            acc[ct] = __builtin_amdgcn_mfma_f32_16x16x32_f16(a, bfrag[ct][ks], acc[ct], 0, 0, 0);
    }

    // epilogue: scale by dis, fp16 store. row = m0 + (lane>>4)*4 + r, col = ct*16 + (lane&15)
    const int rbase = m0 + (lane >> 4) * 4;
#pragma unroll
    for (int r = 0; r < 4; ++r) {
        int n = n0 + rbase + r;
        if (n < N) {
            float sc = dis[n];
#pragma unroll
            for (int ct = 0; ct < 4; ++ct)
                Y[(size_t)n * 64 + ct * 16 + col] = (__half)(acc[ct][r] * sc);
        }
    }
}

// T'[n,c] = dis[n] * ( relu(inv[n]*H'[n,:64]+b1) @ W2[:,c] ); scaled fp16 in/out.
__global__ __launch_bounds__(256) void k_gemm2(const __half* __restrict__ H,
                                               const float* __restrict__ b1,
                                               const float* __restrict__ W2,
                                               const float* __restrict__ dis,
                                               const float* __restrict__ inv,
                                               __half* __restrict__ T, int N) {
    __shared__ float sh[64][68];
    __shared__ float sw[64][68];
    const int tid = threadIdx.x;
    const int n0 = blockIdx.x * 64;
    const bool full = (n0 + 64 <= N);
#pragma unroll
    for (int j = 0; j < 4; ++j) {
        int idx = (tid + j * 256) * 4;
        int k = idx >> 6, h = idx & 63;
        float4 v = make_float4(0.f, 0.f, 0.f, 0.f);
        if (h < 40) v = *reinterpret_cast<const float4*>(W2 + k * 40 + h);
        *reinterpret_cast<float4*>(&sw[k][h]) = v;
    }
#pragma unroll
    for (int j = 0; j < 2; ++j) {
        int idx = (tid + j * 256) * 8;
        int n = idx >> 6, k = idx & 63;
        float v[8];
        if (full || n0 + n < N) {
            float iv = inv[n0 + n];
            h8 hv = *reinterpret_cast<const h8*>(H + (size_t)(n0 + n) * 64 + k);
            float2 f0 = __half22float2(hv.a), f1 = __half22float2(hv.b);
            float2 f2 = __half22float2(hv.c), f3 = __half22float2(hv.d);
            v[0] = f0.x; v[1] = f0.y; v[2] = f1.x; v[3] = f1.y;
            v[4] = f2.x; v[5] = f2.y; v[6] = f3.x; v[7] = f3.y;
#pragma unroll
            for (int q = 0; q < 8; ++q) v[q] = fmaxf(v[q] * iv + b1[k + q], 0.f);
        } else {
#pragma unroll
            for (int q = 0; q < 8; ++q) v[q] = 0.f;
        }
#pragma unroll
        for (int q = 0; q < 8; ++q) sh[n][k + q] = v[q];
    }
    __syncthreads();
    const int lane = tid & 63, wid = tid >> 6;
    const int h0 = (lane & 15) * 4;
    const int nb = wid * 16 + (lane >> 4) * 4;
    float4 a0 = {0,0,0,0}, a1 = {0,0,0,0}, a2 = {0,0,0,0}, a3 = {0,0,0,0};
#define FMA4(a, s, v) { (a).x += (s) * (v).x; (a).y += (s) * (v).y; \
                        (a).z += (s) * (v).z; (a).w += (s) * (v).w; }
#pragma unroll 4
    for (int k0 = 0; k0 < 64; k0 += 4) {
        float4 x0 = *reinterpret_cast<float4*>(&sh[nb + 0][k0]);
        float4 x1 = *reinterpret_cast<float4*>(&sh[nb + 1][k0]);
        float4 x2 = *reinterpret_cast<float4*>(&sh[nb + 2][k0]);
        float4 x3 = *reinterpret_cast<float4*>(&sh[nb + 3][k0]);
        float4 w0 = *reinterpret_cast<float4*>(&sw[k0 + 0][h0]);
        float4 w1 = *reinterpret_cast<float4*>(&sw[k0 + 1][h0]);
        float4 w2 = *reinterpret_cast<float4*>(&sw[k0 + 2][h0]);
        float4 w3 = *reinterpret_cast<float4*>(&sw[k0 + 3][h0]);
        FMA4(a0, x0.x, w0); FMA4(a0, x0.y, w1); FMA4(a0, x0.z, w2); FMA4(a0, x0.w, w3);
        FMA4(a1, x1.x, w0); FMA4(a1, x1.y, w1); FMA4(a1, x1.z, w2); FMA4(a1, x1.w, w3);
        FMA4(a2, x2.x, w0); FMA4(a2, x2.y, w1); FMA4(a2, x2.z, w2); FMA4(a2, x2.w, w3);
        FMA4(a3, x3.x, w0); FMA4(a3, x3.y, w1); FMA4(a3, x3.z, w2); FMA4(a3, x3.w, w3);
    }
    if (h0 < 40) {
        int n = n0 + nb;
#pragma unroll
        for (int r = 0; r < 4; ++r) {
            float4 a = (r == 0) ? a0 : (r == 1) ? a1 : (r == 2) ? a2 : a3;
            if (n + r < N) {
                float sc = dis[n + r];
                h4 o;
                o.a = __float22half2_rn(make_float2(a.x * sc, a.y * sc));
                o.b = __float22half2_rn(make_float2(a.z * sc, a.w * sc));
                *reinterpret_cast<h4*>(T + (size_t)(n + r) * 40 + h0) = o;
            }
        }
    }
}

// out[n,c] = log_softmax(inv[n]*T'[n,:40] + b2), T' scaled fp16. One wave/node.
__global__ void k_bias_lsm(const __half* __restrict__ T, const float* __restrict__ b2,
                           const float* __restrict__ inv, float* __restrict__ Y, int N) {
    int gid = blockIdx.x * blockDim.x + threadIdx.x;
    int node = gid >> 6;
    int lane = threadIdx.x & 63;
    if (node >= N) return;
    float iv = inv[node];
    float v = (lane < 40) ? __half2float(T[(size_t)node * 40 + lane]) * iv + b2[lane]
                          : -INFINITY;
    float m = v;
    for (int off = 32; off >= 1; off >>= 1) m = fmaxf(m, __shfl_xor(m, off));
    float ev = (lane < 40) ? expf(v - m) : 0.0f;
    float s = ev;
    for (int off = 32; off >= 1; off >>= 1) s += __shfl_xor(s, off);
    if (lane < 40) Y[(size_t)node * 40 + lane] = v - m - logf(s);
}

// ---------------- launch ----------------

extern "C" void kernel_launch(void* const* d_in, const int* in_sizes, int n_in,
                              void* d_out, int out_size, void* d_ws, size_t ws_size,
                              hipStream_t stream) {
    const float* x  = (const float*)d_in[0];
    const int*   ei = (const int*)d_in[1];
    const float* W1 = (const float*)d_in[2];
    const float* b1 = (const float*)d_in[3];
    const float* W2 = (const float*)d_in[4];
    const float* b2 = (const float*)d_in[5];
    float* out = (float*)d_out;

    const int H = in_sizes[3];            // 64
    const int F = in_sizes[2] / H;        // 128
    const int N = in_sizes[0] / F;        // 100000
    const int E = in_sizes[1] / 2;        // 1600000
    (void)ws_size; (void)n_in; (void)out_size;

    const int* src = ei;
    const int* dst = ei + E;
    const int NSB = div_up(N, SCH);               // node-scan blocks (49)
    const int NBK = div_up(N, BKN);               // node buckets (391)
    const int lenA = NBK * PM;                    // histA length (100096)
    const int NSA = div_up(lenA, SCH);            // histA-scan blocks (49)

    // workspace layout
    const int Npad = (N + 256) & ~255;            // covers N+1
    float* dis   = (float*)d_ws;                  // N
    float* inv   = dis + Npad;                    // N
    int*   cnt   = (int*)(inv + Npad);            // N
    int*   rp    = cnt + Npad;                    // N+1
    int*   cur   = rp + Npad;                     // N
    int*   bsum  = cur + Npad;                    // 256 pad
    int*   bsumA = bsum + 256;                    // 256 pad (tot at +128)
    int*   histA = bsumA + 256;                   // lenA
    int*   csrc  = histA + ((lenA + 255) & ~255); // E
    __half* bufA = (__half*)(csrc + ((E + 255) & ~255));   // N*64 halfs
    __half* bufB = bufA + (size_t)N * 64;                  // N*64 halfs
    unsigned* pairs = (unsigned*)bufB;            // E u32, dead until prop1

    const int B = 256;

    // ---- CSR build (no per-edge global atomics anywhere) ----
    k_histA<<<PM, 256, 0, stream>>>(dst, histA, E, NBK);
    k_scan_part<<<NSA, 256, 0, stream>>>(histA, bsumA, lenA);
    k_scan_bsums<<<1, 1024, 0, stream>>>(bsumA, bsumA + 128, NSA);
    k_scan_apply_plain<<<NSA, 256, 0, stream>>>(histA, bsumA, lenA);
    k_partitionA<<<PM, 256, 0, stream>>>(src, dst, histA, pairs, E, NBK);
    k_cntB<<<NBK, 256, 0, stream>>>(pairs, histA, cnt, E, N, NBK);
    k_scan_part<<<NSB, 256, 0, stream>>>(cnt, bsum, N);
    k_scan_bsums<<<1, 1024, 0, stream>>>(bsum, rp + N, NSB);
    k_scan_apply<<<NSB, 256, 0, stream>>>(cnt, bsum, rp, cur, dis, inv, N);
    k_placeB<<<NBK, 256, 0, stream>>>(pairs, rp, cur, csrc, N);

    // ---- layer 1 (commuted, scaled form): Y' = dis*(X@W1) via MFMA, 2 props F=64 ----
    k_gemm1<<<div_up(N, 64), 256, 0, stream>>>(x, W1, dis, bufA, N);
    k_prop_h<64><<<PROPG, B, 0, stream>>>(rp, csrc, dis, bufA, bufB, N);
    k_prop_h<64><<<PROPG, B, 0, stream>>>(rp, csrc, dis, bufB, bufA, N);

    // ---- layer 2 (commuted, scaled form): T' = dis*(relu(inv*h'+b1)@W2), 2 props F=40 ----
    k_gemm2<<<div_up(N, 64), 256, 0, stream>>>(bufA, b1, W2, dis, inv, bufB, N);
    k_prop_h<40><<<PROPG, B, 0, stream>>>(rp, csrc, dis, bufB, bufA, N);
    k_prop_h<40><<<PROPG, B, 0, stream>>>(rp, csrc, dis, bufA, bufB, N);

    // ---- epilogue: out = log_softmax(inv*T' + b2) ----
    k_bias_lsm<<<div_up((long long)N * 64, 256), 256, 0, stream>>>(bufB, b2, inv, out, N);
}

// Round 19
// 252.355 us; speedup vs baseline: 1.1166x; 1.0743x over previous
//
#include <hip/hip_runtime.h>
#include <hip/hip_fp16.h>
#include <math.h>

__host__ __device__ static inline int div_up(long long a, long long b) { return (int)((a + b - 1) / b); }

#define SCH 2048              // scan chunk per block
#define PM 256                // edge chunks (one block per chunk in histA/partitionA)
#define BKN 256               // nodes per bucket (shift 8); buckets 256-aligned
#define CAP 8192              // LDS staging capacity (edges) in k_placeB2
#define PROPG 2048            // persistent blocks for propagation

struct h8 { __half2 a, b, c, d; };   // 8 halfs = 16 B
struct h4 { __half2 a, b; };         // 4 halfs = 8 B

typedef _Float16 half8v __attribute__((ext_vector_type(8)));
typedef float f32x4v __attribute__((ext_vector_type(4)));

__device__ inline int nt_load1(const int* p) {
    return __builtin_nontemporal_load(p);
}
__device__ inline h4 f4toh4(float4 v) {
    h4 o;
    o.a = __float22half2_rn(make_float2(v.x, v.y));
    o.b = __float22half2_rn(make_float2(v.z, v.w));
    return o;
}

// ---------------- CSR build (zero per-edge global atomics) ----------------

// Bucket-level LDS histogram of dst; out slice-major histA[b*PM + c].
__global__ __launch_bounds__(256) void k_histA(const int* __restrict__ dst,
                                               int* __restrict__ histA,
                                               int E, int NBK) {
    __shared__ int h[1024];               // NBK <= 1024
    const int tid = threadIdx.x, c = blockIdx.x;
    for (int i = tid; i < NBK; i += 256) h[i] = 0;
    __syncthreads();
    const int ce = (div_up(E, PM) + 3) & ~3;
    const int e0 = c * ce, e1 = min(E, e0 + ce);
    int i = e0 + tid * 4;
    for (; i + 3 < e1; i += 256 * 4) {
        int4 d = *reinterpret_cast<const int4*>(dst + i);
        atomicAdd(&h[d.x >> 8], 1);
        atomicAdd(&h[d.y >> 8], 1);
        atomicAdd(&h[d.z >> 8], 1);
        atomicAdd(&h[d.w >> 8], 1);
    }
    for (int j = i; j < e1; ++j) atomicAdd(&h[dst[j] >> 8], 1);
    __syncthreads();
    for (int b = tid; b < NBK; b += 256) histA[b * PM + c] = h[b];
}

// Scan phase 1: per-block sums of SCH-element chunks (generic length).
__global__ void k_scan_part(const int* __restrict__ a, int* __restrict__ bsum, int len) {
    __shared__ int ws[4];
    int base = blockIdx.x * SCH + threadIdx.x * 8;
    int t = 0;
#pragma unroll
    for (int j = 0; j < 8; ++j) {
        int idx = base + j;
        if (idx < len) t += a[idx];
    }
    for (int off = 32; off >= 1; off >>= 1) t += __shfl_xor(t, off);
    int lane = threadIdx.x & 63, wid = threadIdx.x >> 6;
    if (lane == 0) ws[wid] = t;
    __syncthreads();
    if (threadIdx.x == 0) bsum[blockIdx.x] = ws[0] + ws[1] + ws[2] + ws[3];
}

// Scan phase 2 (block sums, NB <= 1024) + grand total -> tot[0].
__global__ void k_scan_bsums(int* __restrict__ bsum, int* __restrict__ tot, int NB) {
    __shared__ int wsum[16];
    int tid = threadIdx.x;
    int v = (tid < NB) ? bsum[tid] : 0;
    int lane = tid & 63, wid = tid >> 6;
    int x = v;
    for (int off = 1; off < 64; off <<= 1) {
        int y = __shfl_up(x, off);
        if (lane >= off) x += y;
    }
    if (lane == 63) wsum[wid] = x;
    __syncthreads();
    if (tid < 16) {
        int s = wsum[tid];
        for (int off = 1; off < 16; off <<= 1) {
            int y = __shfl_up(s, off);
            if (tid >= off) s += y;
        }
        wsum[tid] = s;
    }
    __syncthreads();
    int woff = (wid > 0) ? wsum[wid - 1] : 0;
    int excl = woff + x - v;
    if (tid < NB) bsum[tid] = excl;
    if (tid == NB - 1) tot[0] = excl + v;
}

// Scan phase 3 (plain, in-place): a <- exclusive_scan(a).
__global__ void k_scan_apply_plain(int* __restrict__ a, const int* __restrict__ bsum,
                                   int len) {
    __shared__ int wsum[4];
    int tid = threadIdx.x;
    int base = blockIdx.x * SCH + tid * 8;
    int v[8];
    int t = 0;
#pragma unroll
    for (int j = 0; j < 8; ++j) {
        int idx = base + j;
        v[j] = (idx < len) ? a[idx] : 0;
        t += v[j];
    }
    int lane = tid & 63, wid = tid >> 6;
    int x = t;
    for (int off = 1; off < 64; off <<= 1) {
        int y = __shfl_up(x, off);
        if (lane >= off) x += y;
    }
    if (lane == 63) wsum[wid] = x;
    __syncthreads();
    int woff = 0;
    for (int w = 0; w < wid; ++w) woff += wsum[w];
    int run = bsum[blockIdx.x] + woff + (x - t);
#pragma unroll
    for (int j = 0; j < 8; ++j) {
        int idx = base + j;
        if (idx < len) a[idx] = run;
        run += v[j];
    }
}

// Partition edges into per-(bucket,chunk) regions via LDS cursors, packed
// uint32 = (src << 8) | (dst & 255). Valid: N < 2^24, buckets 256-aligned.
__global__ __launch_bounds__(256) void k_partitionA(
        const int* __restrict__ src, const int* __restrict__ dst,
        const int* __restrict__ pbase, unsigned* __restrict__ pairs, int E, int NBK) {
    __shared__ int curb[1024];
    const int tid = threadIdx.x, c = blockIdx.x;
    for (int b = tid; b < NBK; b += 256) curb[b] = pbase[b * PM + c];
    __syncthreads();
    const int ce = (div_up(E, PM) + 3) & ~3;
    const int e0 = c * ce, e1 = min(E, e0 + ce);
    int i = e0 + tid * 4;
    for (; i + 3 < e1; i += 256 * 4) {
        int4 d4 = *reinterpret_cast<const int4*>(dst + i);
        int4 s4 = *reinterpret_cast<const int4*>(src + i);
        int p0 = atomicAdd(&curb[d4.x >> 8], 1); pairs[p0] = ((unsigned)s4.x << 8) | (d4.x & 255);
        int p1 = atomicAdd(&curb[d4.y >> 8], 1); pairs[p1] = ((unsigned)s4.y << 8) | (d4.y & 255);
        int p2 = atomicAdd(&curb[d4.z >> 8], 1); pairs[p2] = ((unsigned)s4.z << 8) | (d4.z & 255);
        int p3 = atomicAdd(&curb[d4.w >> 8], 1); pairs[p3] = ((unsigned)s4.w << 8) | (d4.w & 255);
    }
    for (int j = i; j < e1; ++j) {
        int d = dst[j];
        int p = atomicAdd(&curb[d >> 8], 1);
        pairs[p] = ((unsigned)src[j] << 8) | (d & 255);
    }
}

// Fused finalize: one block per bucket. Counts per-node degrees (LDS),
// block-local exclusive scan -> emits rp/dis/inv, then LDS counting-sort
// place -> coalesced csrc. Bucket base comes free: pbase[b*PM] == rp[n0].
__global__ __launch_bounds__(256) void k_placeB2(
        const unsigned* __restrict__ pairs, const int* __restrict__ pbase,
        int* __restrict__ rp, float* __restrict__ dis, float* __restrict__ inv,
        int* __restrict__ csrc, int E, int N, int NBK) {
    __shared__ int cnt256[BKN];
    __shared__ int wsum[4];
    __shared__ int stage[CAP];
    const int b = blockIdx.x;
    const int tid = threadIdx.x;
    const int n0 = b * BKN;
    const int base = pbase[b * PM];
    const int end = (b + 1 < NBK) ? pbase[(b + 1) * PM] : E;
    const int cntb = end - base;
    cnt256[tid] = 0;
    __syncthreads();
    for (int i = base + tid; i < end; i += 256)
        atomicAdd(&cnt256[pairs[i] & 255], 1);
    __syncthreads();
    // block-local exclusive scan of the 256 counts
    const int v = cnt256[tid];
    const int lane = tid & 63, wid = tid >> 6;
    int x = v;
    for (int off = 1; off < 64; off <<= 1) {
        int y = __shfl_up(x, off);
        if (lane >= off) x += y;
    }
    if (lane == 63) wsum[wid] = x;
    __syncthreads();
    int woff = 0;
    for (int w = 0; w < wid; ++w) woff += wsum[w];
    const int ex = woff + x - v;
    // emit rp / dis / inv
    const int n = n0 + tid;
    if (n < N) {
        rp[n] = base + ex;
        float dg = (float)v + 1.0f;
        dis[n] = rsqrtf(dg);
        inv[n] = sqrtf(dg);
    }
    if (b == NBK - 1 && tid == 255) rp[N] = base + ex + v;   // == E
    __syncthreads();
    cnt256[tid] = ex;                 // reuse as place cursor
    __syncthreads();
    if (cntb <= CAP) {
        for (int i = base + tid; i < end; i += 256) {
            unsigned pr = pairs[i];
            int p = atomicAdd(&cnt256[pr & 255], 1);
            stage[p] = (int)(pr >> 8);
        }
        __syncthreads();
        for (int i = tid; i < cntb; i += 256) csrc[base + i] = stage[i];
    } else {
        for (int i = base + tid; i < end; i += 256) {
            unsigned pr = pairs[i];
            int p = atomicAdd(&cnt256[pr & 255], 1);
            csrc[base + p] = (int)(pr >> 8);
        }
    }
}

// ---------------- propagation (scaled form: buffers hold h' = dis*h) ----------------
// h_out'[n] = dis[n]^2 * ( h'[n] + sum_{s in N(n)} h'[s] )  -- no per-edge weights.

__device__ inline void add_h8(float* acc, const h8& v) {
    float2 f0 = __half22float2(v.a), f1 = __half22float2(v.b);
    float2 f2 = __half22float2(v.c), f3 = __half22float2(v.d);
    acc[0] += f0.x; acc[1] += f0.y;
    acc[2] += f1.x; acc[3] += f1.y;
    acc[4] += f2.x; acc[5] += f2.y;
    acc[6] += f3.x; acc[7] += f3.y;
}

template<int F>  // F in halfs per row; TPE = F/8
__global__ __launch_bounds__(256) void k_prop_h(
        const int* __restrict__ rp, const int* __restrict__ csrc,
        const float* __restrict__ dis,
        const __half* __restrict__ hin, __half* __restrict__ hout, int N) {
    constexpr int TPE = F / 8;
    const long long total = (long long)N * TPE;
    const long long stride = (long long)gridDim.x * 256;
    for (long long t = (long long)blockIdx.x * 256 + threadIdx.x; t < total; t += stride) {
        int n = (int)(t / TPE);
        int l = (int)(t % TPE);
        float acc[8];
        {
            h8 v = *reinterpret_cast<const h8*>(hin + (size_t)n * F + 8 * l);
#pragma unroll
            for (int j = 0; j < 8; ++j) acc[j] = 0.f;
            add_h8(acc, v);
        }
        int e = rp[n], end = rp[n + 1];
        for (; e + 7 < end; e += 8) {
            int s[8];
            h8 v[8];
#pragma unroll
            for (int j = 0; j < 8; ++j) s[j] = nt_load1(csrc + e + j);
#pragma unroll
            for (int j = 0; j < 8; ++j)
                v[j] = *reinterpret_cast<const h8*>(hin + (size_t)s[j] * F + 8 * l);
#pragma unroll
            for (int j = 0; j < 8; ++j) add_h8(acc, v[j]);
        }
        for (; e < end; ++e) {
            int s = nt_load1(csrc + e);
            h8 v = *reinterpret_cast<const h8*>(hin + (size_t)s * F + 8 * l);
            add_h8(acc, v);
        }
        float dn = dis[n];
        float d2 = dn * dn;
        h8 o;
        o.a = __float22half2_rn(make_float2(acc[0] * d2, acc[1] * d2));
        o.b = __float22half2_rn(make_float2(acc[2] * d2, acc[3] * d2));
        o.c = __float22half2_rn(make_float2(acc[4] * d2, acc[5] * d2));
        o.d = __float22half2_rn(make_float2(acc[6] * d2, acc[7] * d2));
        *reinterpret_cast<h8*>(hout + (size_t)n * F + 8 * l) = o;
    }
}

// ---------------- dense layers (MFMA) ----------------
// Frag layout (m89-verified family): A: row=lane&15, k=(lane>>4)*8+j;
// B: k=(lane>>4)*8+j, col=lane&15; C/D: col=lane&15, row=(lane>>4)*4+r.

// GEMM1 via MFMA: Y'[n,h] = dis[n] * (X[n,:128] @ W1[:,h]), fp16 out.
__global__ __launch_bounds__(256) void k_gemm1(const float* __restrict__ X,
                                               const float* __restrict__ W,
                                               const float* __restrict__ dis,
                                               __half* __restrict__ Y, int N) {
    __shared__ __half sx[64][136];      // row stride 272B: 16B-aligned
    const int tid = threadIdx.x;
    const int lane = tid & 63, wv = tid >> 6;
    const int n0 = blockIdx.x * 64;
    const bool full = (n0 + 64 <= N);
    const int krow = (lane >> 4) * 8;
    const int col = lane & 15;

    half8v bfrag[4][4];
#pragma unroll
    for (int ct = 0; ct < 4; ++ct)
#pragma unroll
        for (int ks = 0; ks < 4; ++ks)
#pragma unroll
            for (int j = 0; j < 8; ++j)
                bfrag[ct][ks][j] = (_Float16)W[(ks * 32 + krow + j) * 64 + ct * 16 + col];

    float4 xr[8];
#pragma unroll
    for (int j = 0; j < 8; ++j) {
        int idx = (tid + j * 256) * 4;
        int n = idx >> 7, k = idx & 127;
        float4 v = make_float4(0.f, 0.f, 0.f, 0.f);
        if (full || n0 + n < N)
            v = *reinterpret_cast<const float4*>(X + (size_t)(n0 + n) * 128 + k);
        xr[j] = v;
    }
#pragma unroll
    for (int j = 0; j < 8; ++j) {
        int idx = (tid + j * 256) * 4;
        int n = idx >> 7, k = idx & 127;
        *reinterpret_cast<h4*>(&sx[n][k]) = f4toh4(xr[j]);
    }
    __syncthreads();

    const int m0 = wv * 16;
    f32x4v acc[4] = {{0,0,0,0},{0,0,0,0},{0,0,0,0},{0,0,0,0}};
#pragma unroll
    for (int ks = 0; ks < 4; ++ks) {
        half8v a = *reinterpret_cast<const half8v*>(&sx[m0 + (lane & 15)][ks * 32 + krow]);
#pragma unroll
        for (int ct = 0; ct < 4; ++ct)
            acc[ct] = __builtin_amdgcn_mfma_f32_16x16x32_f16(a, bfrag[ct][ks], acc[ct], 0, 0, 0);
    }

    const int rbase = m0 + (lane >> 4) * 4;
#pragma unroll
    for (int r = 0; r < 4; ++r) {
        int n = n0 + rbase + r;
        if (n < N) {
            float sc = dis[n];
#pragma unroll
            for (int ct = 0; ct < 4; ++ct)
                Y[(size_t)n * 64 + ct * 16 + col] = (__half)(acc[ct][r] * sc);
        }
    }
}

// GEMM2 via MFMA: T'[n,c] = dis[n] * ( relu(inv[n]*H'[n,:64]+b1) @ W2[:,c] ),
// c < 40 (3 col-tiles, zero-padded). relu/bias/inv fused into fp16 staging.
__global__ __launch_bounds__(256) void k_gemm2(const __half* __restrict__ H,
                                               const float* __restrict__ b1,
                                               const float* __restrict__ W2,
                                               const float* __restrict__ dis,
                                               const float* __restrict__ inv,
                                               __half* __restrict__ T, int N) {
    __shared__ __half sh[64][72];       // row stride 144B: 16B-aligned
    const int tid = threadIdx.x;
    const int lane = tid & 63, wv = tid >> 6;
    const int n0 = blockIdx.x * 64;
    const bool full = (n0 + 64 <= N);
    const int krow = (lane >> 4) * 8;
    const int col = lane & 15;

    // B frags from W2 (64 x 40 f32, row-major), cols >= 40 zeroed
    half8v bfrag[3][2];
#pragma unroll
    for (int ct = 0; ct < 3; ++ct)
#pragma unroll
        for (int ks = 0; ks < 2; ++ks)
#pragma unroll
            for (int j = 0; j < 8; ++j) {
                int c = ct * 16 + col;
                bfrag[ct][ks][j] = (c < 40) ? (_Float16)W2[(ks * 32 + krow + j) * 40 + c]
                                            : (_Float16)0.f;
            }

    // stage relu(inv*H' + b1) as fp16 (each thread 2 x h8)
#pragma unroll
    for (int j = 0; j < 2; ++j) {
        int idx = (tid + j * 256) * 8;
        int n = idx >> 6, k = idx & 63;
        float v[8];
        if (full || n0 + n < N) {
            float iv = inv[n0 + n];
            h8 hv = *reinterpret_cast<const h8*>(H + (size_t)(n0 + n) * 64 + k);
            float2 f0 = __half22float2(hv.a), f1 = __half22float2(hv.b);
            float2 f2 = __half22float2(hv.c), f3 = __half22float2(hv.d);
            v[0] = f0.x; v[1] = f0.y; v[2] = f1.x; v[3] = f1.y;
            v[4] = f2.x; v[5] = f2.y; v[6] = f3.x; v[7] = f3.y;
#pragma unroll
            for (int q = 0; q < 8; ++q) v[q] = fmaxf(v[q] * iv + b1[k + q], 0.f);
        } else {
#pragma unroll
            for (int q = 0; q < 8; ++q) v[q] = 0.f;
        }
        h8 o;
        o.a = __float22half2_rn(make_float2(v[0], v[1]));
        o.b = __float22half2_rn(make_float2(v[2], v[3]));
        o.c = __float22half2_rn(make_float2(v[4], v[5]));
        o.d = __float22half2_rn(make_float2(v[6], v[7]));
        *reinterpret_cast<h8*>(&sh[n][k]) = o;
    }
    __syncthreads();

    const int m0 = wv * 16;
    f32x4v acc[3] = {{0,0,0,0},{0,0,0,0},{0,0,0,0}};
#pragma unroll
    for (int ks = 0; ks < 2; ++ks) {
        half8v a = *reinterpret_cast<const half8v*>(&sh[m0 + (lane & 15)][ks * 32 + krow]);
#pragma unroll
        for (int ct = 0; ct < 3; ++ct)
            acc[ct] = __builtin_amdgcn_mfma_f32_16x16x32_f16(a, bfrag[ct][ks], acc[ct], 0, 0, 0);
    }

    const int rbase = m0 + (lane >> 4) * 4;
#pragma unroll
    for (int r = 0; r < 4; ++r) {
        int n = n0 + rbase + r;
        if (n < N) {
            float sc = dis[n];
#pragma unroll
            for (int ct = 0; ct < 3; ++ct) {
                int c = ct * 16 + col;
                if (c < 40) T[(size_t)n * 40 + c] = (__half)(acc[ct][r] * sc);
            }
        }
    }
}

// out[n,c] = log_softmax(inv[n]*T'[n,:40] + b2), T' scaled fp16. One wave/node.
__global__ void k_bias_lsm(const __half* __restrict__ T, const float* __restrict__ b2,
                           const float* __restrict__ inv, float* __restrict__ Y, int N) {
    int gid = blockIdx.x * blockDim.x + threadIdx.x;
    int node = gid >> 6;
    int lane = threadIdx.x & 63;
    if (node >= N) return;
    float iv = inv[node];
    float v = (lane < 40) ? __half2float(T[(size_t)node * 40 + lane]) * iv + b2[lane]
                          : -INFINITY;
    float m = v;
    for (int off = 32; off >= 1; off >>= 1) m = fmaxf(m, __shfl_xor(m, off));
    float ev = (lane < 40) ? expf(v - m) : 0.0f;
    float s = ev;
    for (int off = 32; off >= 1; off >>= 1) s += __shfl_xor(s, off);
    if (lane < 40) Y[(size_t)node * 40 + lane] = v - m - logf(s);
}

// ---------------- launch ----------------

extern "C" void kernel_launch(void* const* d_in, const int* in_sizes, int n_in,
                              void* d_out, int out_size, void* d_ws, size_t ws_size,
                              hipStream_t stream) {
    const float* x  = (const float*)d_in[0];
    const int*   ei = (const int*)d_in[1];
    const float* W1 = (const float*)d_in[2];
    const float* b1 = (const float*)d_in[3];
    const float* W2 = (const float*)d_in[4];
    const float* b2 = (const float*)d_in[5];
    float* out = (float*)d_out;

    const int H = in_sizes[3];            // 64
    const int F = in_sizes[2] / H;        // 128
    const int N = in_sizes[0] / F;        // 100000
    const int E = in_sizes[1] / 2;        // 1600000
    (void)ws_size; (void)n_in; (void)out_size;

    const int* src = ei;
    const int* dst = ei + E;
    const int NBK = div_up(N, BKN);               // node buckets (391)
    const int lenA = NBK * PM;                    // histA length (100096)
    const int NSA = div_up(lenA, SCH);            // histA-scan blocks (49)

    // workspace layout
    const int Npad = (N + 256) & ~255;            // covers N+1
    float* dis   = (float*)d_ws;                  // N
    float* inv   = dis + Npad;                    // N
    int*   rp    = (int*)(inv + Npad);            // N+1
    int*   bsumA = rp + Npad;                     // 256 pad (tot at +128)
    int*   histA = bsumA + 256;                   // lenA
    int*   csrc  = histA + ((lenA + 255) & ~255); // E
    __half* bufA = (__half*)(csrc + ((E + 255) & ~255));   // N*64 halfs
    __half* bufB = bufA + (size_t)N * 64;                  // N*64 halfs
    unsigned* pairs = (unsigned*)bufB;            // E u32, dead until prop1

    const int B = 256;

    // ---- CSR build (fused finalize; no per-edge global atomics) ----
    k_histA<<<PM, 256, 0, stream>>>(dst, histA, E, NBK);
    k_scan_part<<<NSA, 256, 0, stream>>>(histA, bsumA, lenA);
    k_scan_bsums<<<1, 1024, 0, stream>>>(bsumA, bsumA + 128, NSA);
    k_scan_apply_plain<<<NSA, 256, 0, stream>>>(histA, bsumA, lenA);
    k_partitionA<<<PM, 256, 0, stream>>>(src, dst, histA, pairs, E, NBK);
    k_placeB2<<<NBK, 256, 0, stream>>>(pairs, histA, rp, dis, inv, csrc, E, N, NBK);

    // ---- layer 1 (commuted, scaled form): Y' = dis*(X@W1) via MFMA, 2 props F=64 ----
    k_gemm1<<<div_up(N, 64), 256, 0, stream>>>(x, W1, dis, bufA, N);
    k_prop_h<64><<<PROPG, B, 0, stream>>>(rp, csrc, dis, bufA, bufB, N);
    k_prop_h<64><<<PROPG, B, 0, stream>>>(rp, csrc, dis, bufB, bufA, N);

    // ---- layer 2 (commuted, scaled form): T' = dis*(relu(inv*h'+b1)@W2) via MFMA, 2 props F=40 ----
    k_gemm2<<<div_up(N, 64), 256, 0, stream>>>(bufA, b1, W2, dis, inv, bufB, N);
    k_prop_h<40><<<PROPG, B, 0, stream>>>(rp, csrc, dis, bufB, bufA, N);
    k_prop_h<40><<<PROPG, B, 0, stream>>>(rp, csrc, dis, bufA, bufB, N);

    // ---- epilogue: out = log_softmax(inv*T' + b2) ----
    k_bias_lsm<<<div_up((long long)N * 64, 256), 256, 0, stream>>>(bufB, b2, inv, out, N);
}